// Round 18
// baseline (734.994 us; speedup 1.0000x reference)
//
#include <hip/hip_runtime.h>
#include <hip/hip_bf16.h>
#include <math.h>

#define NN    50000
#define EE    800000
#define IN_F  256
#define HH    4
#define DD    32
#define OUT_F 128
#define ALPHA 0.2f

#define NODE_GB 782     // ceil(NN/64)
#define EDGE_GB 12500   // EE/64
#define HIST_GB 3125    // EE/256
#define SCAT_GB 3125
#define AGG_BLK 128
#define AGG_GB  (EE / AGG_BLK)   // 6250

typedef float f32x4 __attribute__((ext_vector_type(4)));
typedef float f32x2 __attribute__((ext_vector_type(2)));
typedef short bf16x8 __attribute__((ext_vector_type(8)));

__device__ __forceinline__ float elu_f(float x) { return x > 0.0f ? x : expm1f(x); }

__device__ __forceinline__ unsigned short f2bf(float x) {
    union { float f; unsigned u; } v; v.f = x;
    unsigned r = (v.u + 0x7FFFu + ((v.u >> 16) & 1u)) >> 16;
    return (unsigned short)r;
}
__device__ __forceinline__ float bf2f(unsigned short h) {
    union { unsigned u; float f; } v; v.u = ((unsigned)h) << 16; return v.f;
}

// ---- setup: pack W (hi/lo bf16 MFMA B-frag) + zero ssum/ret1 + dst-histogram.
#define PREP_B 128
#define ZS_B   196    // 50000 float4
#define ZR_B   6250   // 1.6M float4
__global__ __launch_bounds__(256) void k_setup0(const float* __restrict__ W,
        unsigned short* __restrict__ Whp, unsigned short* __restrict__ Wlp,
        float4* __restrict__ ssum4, float4* __restrict__ ret14,
        const int* __restrict__ dst, int* __restrict__ hist) {
    const int b = blockIdx.x, tid = threadIdx.x;
    if (b < PREP_B) {
        int i = b * 256 + tid;                 // 32768 total
        int j = i & 7, lane = (i >> 3) & 63, cf = (i >> 9) & 7, t = i >> 12;
        int krow = 32 * t + 8 * (lane >> 4) + j;
        int col  = 16 * cf + (lane & 15);
        float x = W[krow * OUT_F + col];
        unsigned short h = f2bf(x);
        Whp[i] = h;
        Wlp[i] = f2bf(x - bf2f(h));
    } else if (b < PREP_B + ZS_B) {
        int i = (b - PREP_B) * 256 + tid;
        if (i < 50000) ssum4[i] = make_float4(0.f, 0.f, 0.f, 0.f);
    } else if (b < PREP_B + ZS_B + ZR_B) {
        int i = (b - PREP_B - ZS_B) * 256 + tid;   // exactly 1.6M
        ret14[i] = make_float4(0.f, 0.f, 0.f, 0.f);
    } else {
        int i = (b - PREP_B - ZS_B - ZR_B) * 256 + tid;   // exactly EE
        atomicAdd(&hist[dst[i]], 1);
    }
}

// ---- K-chunked fused GEMM body (64 rows x 128 cols, K=256, 4 chunks of 64),
// split-bf16 hi/lo 3-MFMA. Distance-2 register A-prefetch: chunk c+2's loads
// issue at chunk c (two xsA/xsB buffers), giving ~660+ cyc/wave of latency
// tolerance vs ~900-cyc HBM-miss latency (prior distance-1 gave only ~330).
// MODE 0: node -> Yh=ft(bf16), o1=a1, o2=a2.
// MODE 1: edge -> Yh = e_ft + ft[src] (bf16, epilogue gather hidden under
//         dot-reduce); o1=exq[E][H]=exp(leaky(logit)); ssum atomicAdd.
template <int MODE>
__device__ __forceinline__ void gemm_body(int bid, const float* __restrict__ X,
        int M,
        const unsigned short* __restrict__ Whp, const unsigned short* __restrict__ Wlp,
        const float* __restrict__ av0, const float* __restrict__ av1,
        const int* __restrict__ src, const int* __restrict__ dst,
        const float* __restrict__ a1, const float* __restrict__ a2,
        const unsigned short* __restrict__ ftin,   // MODE1: ft (bf16) for gather
        unsigned short* __restrict__ Yh,
        float* __restrict__ o1, float* __restrict__ o2,
        float* __restrict__ ssum) {
    // 32 KB: A-tile dbuf hi/lo planes; head reused for p/q staging after MFMA.
    __shared__ char smem[32768];

    const int tid = threadIdx.x;
    const int w = tid >> 6;          // wave = head
    const int l = tid & 63;
    const int base = bid * 64;

    // hoisted edge metadata loads
    int s_e = 0, t_e = 0;
    if (MODE == 1) { s_e = src[base + l]; t_e = dst[base + l]; }

    const int srow = tid >> 2;                 // 0..63
    const int scg  = tid & 3;                  // 0..3
    int gr = base + srow; if (gr > M - 1) gr = M - 1;
    const float* xp = X + (size_t)gr * IN_F + scg * 16;

    // chunk k's A-data lives in (k&1) ? xsB : xsA
    float4 xsA[4], xsB[4];
    #pragma unroll
    for (int q = 0; q < 4; ++q) xsA[q] = *(const float4*)(xp + q * 4);
    #pragma unroll
    for (int q = 0; q < 4; ++q) xsB[q] = *(const float4*)(xp + 64 + q * 4);

    auto cvtwrite = [&](int buf, const float4* xsrc) {
        unsigned short h[16], lo[16];
        const float* xf = (const float*)xsrc;
        #pragma unroll
        for (int k = 0; k < 16; ++k) {
            h[k]  = f2bf(xf[k]);
            lo[k] = f2bf(xf[k] - bf2f(h[k]));
        }
        const unsigned sw = (unsigned)((srow & 7) << 4);
        const unsigned b0 = (unsigned)(srow * 128 + scg * 32) ^ sw;
        const unsigned b1 = (unsigned)(srow * 128 + scg * 32 + 16) ^ sw;
        char* ph = smem + (buf * 2 + 0) * 8192;
        char* pl = smem + (buf * 2 + 1) * 8192;
        *(bf16x8*)(ph + b0) = *(const bf16x8*)(h);
        *(bf16x8*)(ph + b1) = *(const bf16x8*)(h + 8);
        *(bf16x8*)(pl + b0) = *(const bf16x8*)(lo);
        *(bf16x8*)(pl + b1) = *(const bf16x8*)(lo + 8);
    };
    cvtwrite(0, xsA);    // chunk 0 -> LDS buf 0 (xsA now dead)

    // dependent gathers fly under chunk 0's MFMAs
    float a1v = 0.f, a2v = 0.f;
    if (MODE == 1) {
        a1v = a1[(size_t)s_e * HH + w];
        a2v = a2[(size_t)t_e * HH + w];
    }

    f32x4 acc[4][2];
    #pragma unroll
    for (int rf = 0; rf < 4; ++rf)
        #pragma unroll
        for (int cf = 0; cf < 2; ++cf)
            acc[rf][cf] = (f32x4){0.f, 0.f, 0.f, 0.f};

    #pragma unroll
    for (int c = 0; c < 4; ++c) {
        // B-frag loads before the barrier (global-only; overlap barrier drain)
        bf16x8 Bh[2][2], Bl[2][2];
        #pragma unroll
        for (int ks = 0; ks < 2; ++ks)
            #pragma unroll
            for (int cf = 0; cf < 2; ++cf) {
                size_t off = ((size_t)((c * 2 + ks) * 8 + (w * 2 + cf)) * 64 + l) * 8;
                Bh[ks][cf] = *(const bf16x8*)(Whp + off);
                Bl[ks][cf] = *(const bf16x8*)(Wlp + off);
            }
        __syncthreads();
        // distance-2 A prefetch: chunk c+2 into the buffer freed by chunk c
        if (c == 0) {
            #pragma unroll
            for (int q = 0; q < 4; ++q)
                xsA[q] = *(const float4*)(xp + 2 * 64 + q * 4);
        } else if (c == 1) {
            #pragma unroll
            for (int q = 0; q < 4; ++q)
                xsB[q] = *(const float4*)(xp + 3 * 64 + q * 4);
        }
        const char* ph = smem + ((c & 1) * 2 + 0) * 8192;
        const char* pl = smem + ((c & 1) * 2 + 1) * 8192;
        #pragma unroll
        for (int rf = 0; rf < 4; ++rf) {
            const int row = rf * 16 + (l & 15);
            const unsigned sw = (unsigned)((row & 7) << 4);
            #pragma unroll
            for (int ks = 0; ks < 2; ++ks) {
                const unsigned ba = (unsigned)(row * 128 + ks * 64 + (l >> 4) * 16) ^ sw;
                bf16x8 ah = *(const bf16x8*)(ph + ba);
                bf16x8 al = *(const bf16x8*)(pl + ba);
                #pragma unroll
                for (int cf = 0; cf < 2; ++cf) {
                    acc[rf][cf] = __builtin_amdgcn_mfma_f32_16x16x32_bf16(ah, Bh[ks][cf], acc[rf][cf], 0, 0, 0);
                    acc[rf][cf] = __builtin_amdgcn_mfma_f32_16x16x32_bf16(al, Bh[ks][cf], acc[rf][cf], 0, 0, 0);
                    acc[rf][cf] = __builtin_amdgcn_mfma_f32_16x16x32_bf16(ah, Bl[ks][cf], acc[rf][cf], 0, 0, 0);
                }
            }
        }
        // stage chunk c+1 (loaded two iterations ago) into the idle LDS buffer
        if (c < 3) cvtwrite((c + 1) & 1, ((c + 1) & 1) ? xsB : xsA);
    }

    // ---- MODE1: issue ft[src] gathers (hide under dot-reduce below) ----
    unsigned short ftv[4][2][4];
    if (MODE == 1) {
        int srow16[16];
        #pragma unroll
        for (int rf = 0; rf < 4; ++rf)
            #pragma unroll
            for (int r = 0; r < 4; ++r)
                srow16[rf * 4 + r] = src[base + rf * 16 + (l >> 4) * 4 + r];
        #pragma unroll
        for (int rf = 0; rf < 4; ++rf)
            #pragma unroll
            for (int cf = 0; cf < 2; ++cf)
                #pragma unroll
                for (int r = 0; r < 4; ++r)
                    ftv[rf][cf][r] = ftin[(size_t)srow16[rf * 4 + r] * OUT_F
                                          + w * 32 + cf * 16 + (l & 15)];
    }

    // ---- attention dots: register-only reduce (hides gather latency) ----
    const float b0 = av0[w * DD + (l & 15)];
    const float b1 = av0[w * DD + 16 + (l & 15)];
    float c0v = 0.f, c1v = 0.f;
    if (MODE == 0) { c0v = av1[w * DD + (l & 15)]; c1v = av1[w * DD + 16 + (l & 15)]; }

    float pv[4][4], qv[4][4];
    #pragma unroll
    for (int rf = 0; rf < 4; ++rf)
        #pragma unroll
        for (int r = 0; r < 4; ++r) {
            pv[rf][r] = acc[rf][0][r] * b0 + acc[rf][1][r] * b1;
            if (MODE == 0) qv[rf][r] = acc[rf][0][r] * c0v + acc[rf][1][r] * c1v;
        }
    #pragma unroll
    for (int o = 1; o <= 8; o <<= 1)
        #pragma unroll
        for (int rf = 0; rf < 4; ++rf)
            #pragma unroll
            for (int r = 0; r < 4; ++r) {
                pv[rf][r] += __shfl_xor(pv[rf][r], o);
                if (MODE == 0) qv[rf][r] += __shfl_xor(qv[rf][r], o);
            }

    // ---- store ft (MODE0) / sumb = e_ft + ft[src] (MODE1) as bf16 ----
    #pragma unroll
    for (int rf = 0; rf < 4; ++rf)
        #pragma unroll
        for (int cf = 0; cf < 2; ++cf)
            #pragma unroll
            for (int r = 0; r < 4; ++r) {
                int grow = base + rf * 16 + (l >> 4) * 4 + r;
                float v = acc[rf][cf][r];
                if (MODE == 1) v += bf2f(ftv[rf][cf][r]);
                if (MODE == 1 || grow < M)
                    Yh[(size_t)grow * OUT_F + w * 32 + cf * 16 + (l & 15)] = f2bf(v);
            }

    float* p_lds = (float*)smem;           // 1 KB overlay (A-tile dead)
    float* q_lds = (float*)(smem + 1024);
    __syncthreads();
    if ((l & 15) == 0) {
        const int hi = l >> 4;
        #pragma unroll
        for (int rf = 0; rf < 4; ++rf)
            #pragma unroll
            for (int r = 0; r < 4; ++r) {
                p_lds[w * 64 + rf * 16 + hi * 4 + r] = pv[rf][r];
                if (MODE == 0) q_lds[w * 64 + rf * 16 + hi * 4 + r] = qv[rf][r];
            }
    }
    __syncthreads();

    const int grow = base + l;
    if (MODE == 0) {
        if (grow < M) {
            o1[(size_t)grow * HH + w] = p_lds[w * 64 + l];
            o2[(size_t)grow * HH + w] = q_lds[w * 64 + l];
        }
    } else {
        float lg = p_lds[w * 64 + l] + a1v + a2v;
        lg = fmaxf(lg, ALPHA * lg);          // leaky_relu
        float exv = expf(lg);                // no max-shift (|lg|max ~70 << 88)
        o1[(size_t)grow * HH + w] = exv;     // [E][H]
        atomicAdd(&ssum[t_e * HH + w], exv);
    }
}

// 256-thread exclusive scan of hist[NN] -> cursor (single block).
__device__ __forceinline__ void scan_body(const int* __restrict__ hist,
        int* __restrict__ cursor) {
    __shared__ int part[256];
    const int t = threadIdx.x;
    const int CH = (NN + 255) / 256;          // 196
    const int b = t * CH;
    int s = 0;
    #pragma unroll 4
    for (int i = 0; i < CH; ++i) {
        int idx = b + i;
        if (idx < NN) s += hist[idx];
    }
    part[t] = s;
    __syncthreads();
    int total = s;
    for (int o = 1; o < 256; o <<= 1) {
        int u = (t >= o) ? part[t - o] : 0;
        __syncthreads();
        part[t] += u;
        __syncthreads();
    }
    int run = part[t] - total;                // exclusive base
    for (int i = 0; i < CH; ++i) {
        int idx = b + i;
        if (idx < NN) {
            cursor[idx] = run;
            run += hist[idx];
        }
    }
}

// node GEMM blocks ∥ scan block (cursor consumed only by NEXT kernel).
__global__ __launch_bounds__(256, 4) void k_ng(const float* __restrict__ nf,
        const unsigned short* __restrict__ Whp, const unsigned short* __restrict__ Wlp,
        const float* __restrict__ attn_l, const float* __restrict__ attn_r,
        unsigned short* __restrict__ ftb,
        float* __restrict__ a1buf, float* __restrict__ a2buf,
        const int* __restrict__ hist, int* __restrict__ cursor) {
    if (blockIdx.x < NODE_GB) {
        gemm_body<0>(blockIdx.x, nf, NN, Whp, Wlp, attn_l, attn_r,
                     nullptr, nullptr, nullptr, nullptr, nullptr,
                     ftb, a1buf, a2buf, nullptr);
    } else {
        scan_body(hist, cursor);
    }
}

// edge GEMM blocks ∥ scatter blocks
__global__ __launch_bounds__(256, 4) void k_eg(const float* __restrict__ ef,
        const unsigned short* __restrict__ Whp, const unsigned short* __restrict__ Wlp,
        const float* __restrict__ attn_e,
        const int* __restrict__ src, const int* __restrict__ dst,
        const float* __restrict__ a1buf, const float* __restrict__ a2buf,
        const unsigned short* __restrict__ ftb,
        unsigned short* __restrict__ sumb, float* __restrict__ exq,
        float* __restrict__ ssum,
        int* __restrict__ cursor, int* __restrict__ order) {
    if (blockIdx.x < EDGE_GB) {
        gemm_body<1>(blockIdx.x, ef, EE, Whp, Wlp, attn_e, nullptr,
                     src, dst, a1buf, a2buf, ftb, sumb, exq, nullptr, ssum);
    } else {
        int i = (blockIdx.x - EDGE_GB) * 256 + threadIdx.x;   // exactly EE
        int pos = atomicAdd(&cursor[dst[i]], 1);
        order[pos] = i;
    }
}

// Edge-centric aggregation over dst-sorted order[]. Block = 128 sorted edges,
// wave w owns rows [32w,32w+32). sumb holds e_ft+ft[src] (bf16). ret2 (never
// re-read) written with non-temporal stores so sumb/exq stay L3-resident.
__global__ __launch_bounds__(256, 8) void k_agg2(const int* __restrict__ order,
        const int* __restrict__ dst,
        const float* __restrict__ exq, const float* __restrict__ ssum,
        const unsigned short* __restrict__ sumb,
        float* __restrict__ ret2, float* __restrict__ node_out) {
    __shared__ int eL[AGG_BLK], dL[AGG_BLK];
    __shared__ int sent[2];
    const int tid = threadIdx.x;
    const int base = blockIdx.x * AGG_BLK;
    if (tid < AGG_BLK) {
        int e = order[base + tid];
        eL[tid] = e;
        dL[tid] = dst[e];
    } else if (tid == AGG_BLK) {
        sent[0] = (blockIdx.x > 0) ? dst[order[base - 1]] : -1;
    } else if (tid == AGG_BLK + 1) {
        sent[1] = (base + AGG_BLK < EE) ? dst[order[base + AGG_BLK]] : -1;
    }
    __syncthreads();

    const int w = tid >> 6, l = tid & 63;
    const int W0 = w * 32, W1 = W0 + 31;
    const int c0 = l * 2, h = l >> 4;

    const int dprev  = (W0 == 0)           ? sent[0] : dL[W0 - 1];
    const int dafter = (W1 == AGG_BLK - 1) ? sent[1] : dL[W1 + 1];

    float acc0 = 0.f, acc1 = 0.f;
    int dcur = dL[W0];
    bool touch_start = true;

    #pragma unroll 4
    for (int r = W0; r <= W1; ++r) {
        const int e = eL[r], d = dL[r];
        if (d != dcur) {       // wave-uniform: flush completed run
            const size_t o = (size_t)dcur * OUT_F + c0;
            if (touch_start && dcur == dprev) {
                atomicAdd(&node_out[o], acc0);
                atomicAdd(&node_out[o + 1], acc1);
            } else {
                *(float2*)(node_out + o) = make_float2(acc0, acc1);
            }
            acc0 = acc1 = 0.f; dcur = d; touch_start = false;
        }
        const float a = exq[(size_t)e * HH + h] * __frcp_rn(ssum[d * HH + h]);
        ushort2 sv = *(const ushort2*)(sumb + (size_t)e * OUT_F + c0);
        float f0 = bf2f(sv.x) * a;
        float f1 = bf2f(sv.y) * a;
        acc0 += f0; acc1 += f1;
        f32x2 outv = {elu_f(f0), elu_f(f1)};
        __builtin_nontemporal_store(outv, (f32x2*)(ret2 + (size_t)e * OUT_F + c0));
    }
    {
        const size_t o = (size_t)dcur * OUT_F + c0;
        const bool at = (touch_start && dcur == dprev) || (dcur == dafter);
        if (at) {
            atomicAdd(&node_out[o], acc0);
            atomicAdd(&node_out[o + 1], acc1);
        } else {
            *(float2*)(node_out + o) = make_float2(acc0, acc1);
        }
    }
}

__global__ __launch_bounds__(256) void k_elu1(const float4* __restrict__ node_out,
        float* __restrict__ ret1) {
    const int i = blockIdx.x * blockDim.x + threadIdx.x;
    if (i < NN * OUT_F / 4) {
        float4 v = node_out[i];
        f32x4 outv = {elu_f(v.x), elu_f(v.y), elu_f(v.z), elu_f(v.w)};
        __builtin_nontemporal_store(outv, (f32x4*)(ret1 + (size_t)i * 4));
    }
}

extern "C" void kernel_launch(void* const* d_in, const int* in_sizes, int n_in,
                              void* d_out, int out_size, void* d_ws, size_t ws_size,
                              hipStream_t stream) {
    const float* nf     = (const float*)d_in[0];
    const float* ef     = (const float*)d_in[1];
    const int*   src    = (const int*)d_in[2];
    const int*   dst    = (const int*)d_in[3];
    const float* W      = (const float*)d_in[4];
    const float* attn_l = (const float*)d_in[5];
    const float* attn_r = (const float*)d_in[6];
    const float* attn_e = (const float*)d_in[7];

    float* ret1 = (float*)d_out;                     // N*128, node_out accum
    float* ret2 = ret1 + (size_t)NN * OUT_F;         // E*128 output

    char* wsp = (char*)d_ws;
    auto take = [&](size_t bytes) { char* p = wsp; wsp += (bytes + 511) & ~size_t(511); return p; };
    unsigned short* ftb = (unsigned short*)take((size_t)NN * OUT_F * 2);  // 12.8 MB
    float* a1buf  = (float*)take((size_t)NN * HH * 4);
    float* a2buf  = (float*)take((size_t)NN * HH * 4);
    float* exq    = (float*)take((size_t)EE * HH * 4);      // 12.8 MB, [E][H]
    float* ssum   = (float*)take((size_t)NN * HH * 4);
    unsigned short* Whp = (unsigned short*)take(32768 * 2);
    unsigned short* Wlp = (unsigned short*)take(32768 * 2);
    int* hist   = (int*)take((size_t)(NN + 16) * 4);
    int* cursor = (int*)take((size_t)NN * 4);
    int* order  = (int*)take((size_t)EE * 4);               // 3.2 MB
    unsigned short* sumb = (unsigned short*)take((size_t)EE * OUT_F * 2); // 204.8 MB

    hipMemsetAsync(hist, 0, (size_t)NN * 4, stream);
    k_setup0<<<PREP_B + ZS_B + ZR_B + HIST_GB, 256, 0, stream>>>(
            W, Whp, Wlp, (float4*)ssum, (float4*)ret1, dst, hist);
    k_ng<<<NODE_GB + 1, 256, 0, stream>>>(nf, Whp, Wlp, attn_l, attn_r,
            ftb, a1buf, a2buf, hist, cursor);
    k_eg<<<EDGE_GB + SCAT_GB, 256, 0, stream>>>(ef, Whp, Wlp, attn_e,
            src, dst, a1buf, a2buf, ftb, sumb, exq, ssum, cursor, order);
    k_agg2<<<AGG_GB, 256, 0, stream>>>(order, dst, exq, ssum, sumb,
                                       ret2, ret1);
    k_elu1<<<(NN * OUT_F / 4 + 255) / 256, 256, 0, stream>>>(
            (const float4*)ret1, ret1);
}

// Round 19
// 710.146 us; speedup vs baseline: 1.0350x; 1.0350x over previous
//
#include <hip/hip_runtime.h>
#include <hip/hip_bf16.h>
#include <math.h>

#define NN    50000
#define EE    800000
#define IN_F  256
#define HH    4
#define DD    32
#define OUT_F 128
#define ALPHA 0.2f

#define NODE_GB 782     // ceil(NN/64)
#define EDGE_GB 12500   // EE/64
#define HIST_GB 3125    // EE/256
#define SCAT_GB 3125
#define AGG_BLK 128
#define AGG_GB  (EE / AGG_BLK)   // 6250

typedef float f32x4 __attribute__((ext_vector_type(4)));
typedef float f32x2 __attribute__((ext_vector_type(2)));
typedef short bf16x8 __attribute__((ext_vector_type(8)));

__device__ __forceinline__ float elu_f(float x) { return x > 0.0f ? x : expm1f(x); }

__device__ __forceinline__ unsigned short f2bf(float x) {
    union { float f; unsigned u; } v; v.f = x;
    unsigned r = (v.u + 0x7FFFu + ((v.u >> 16) & 1u)) >> 16;
    return (unsigned short)r;
}
__device__ __forceinline__ float bf2f(unsigned short h) {
    union { unsigned u; float f; } v; v.u = ((unsigned)h) << 16; return v.f;
}

// ---- setup: pack W (hi/lo bf16 MFMA B-frag) + zero ssum/ret1 + dst-histogram.
#define PREP_B 128
#define ZS_B   196    // 50000 float4
#define ZR_B   6250   // 1.6M float4
__global__ __launch_bounds__(256) void k_setup0(const float* __restrict__ W,
        unsigned short* __restrict__ Whp, unsigned short* __restrict__ Wlp,
        float4* __restrict__ ssum4, float4* __restrict__ ret14,
        const int* __restrict__ dst, int* __restrict__ hist) {
    const int b = blockIdx.x, tid = threadIdx.x;
    if (b < PREP_B) {
        int i = b * 256 + tid;                 // 32768 total
        int j = i & 7, lane = (i >> 3) & 63, cf = (i >> 9) & 7, t = i >> 12;
        int krow = 32 * t + 8 * (lane >> 4) + j;
        int col  = 16 * cf + (lane & 15);
        float x = W[krow * OUT_F + col];
        unsigned short h = f2bf(x);
        Whp[i] = h;
        Wlp[i] = f2bf(x - bf2f(h));
    } else if (b < PREP_B + ZS_B) {
        int i = (b - PREP_B) * 256 + tid;
        if (i < 50000) ssum4[i] = make_float4(0.f, 0.f, 0.f, 0.f);
    } else if (b < PREP_B + ZS_B + ZR_B) {
        int i = (b - PREP_B - ZS_B) * 256 + tid;   // exactly 1.6M
        ret14[i] = make_float4(0.f, 0.f, 0.f, 0.f);
    } else {
        int i = (b - PREP_B - ZS_B - ZR_B) * 256 + tid;   // exactly EE
        atomicAdd(&hist[dst[i]], 1);
    }
}

// ---- K-chunked fused GEMM body (64 rows x 128 cols, K=256, 4 chunks of 64),
// split-bf16 hi/lo 3-MFMA. B-fragment loads hoisted ABOVE the per-chunk
// barrier (global-only, no LDS dependence) so their L2 latency overlaps the
// barrier drain.
// MODE 0: node -> Yh=ft(bf16), o1=a1, o2=a2.
// MODE 1: edge -> Yh = e_ft + ft[src] (bf16, epilogue gather hidden under
//         dot-reduce); o1=exq[E][H]=exp(leaky(logit)); ssum atomicAdd.
template <int MODE>
__device__ __forceinline__ void gemm_body(int bid, const float* __restrict__ X,
        int M,
        const unsigned short* __restrict__ Whp, const unsigned short* __restrict__ Wlp,
        const float* __restrict__ av0, const float* __restrict__ av1,
        const int* __restrict__ src, const int* __restrict__ dst,
        const float* __restrict__ a1, const float* __restrict__ a2,
        const unsigned short* __restrict__ ftin,   // MODE1: ft (bf16) for gather
        unsigned short* __restrict__ Yh,
        float* __restrict__ o1, float* __restrict__ o2,
        float* __restrict__ ssum) {
    // 32 KB: A-tile dbuf hi/lo planes; head reused for p/q staging after MFMA.
    __shared__ char smem[32768];

    const int tid = threadIdx.x;
    const int w = tid >> 6;          // wave = head
    const int l = tid & 63;
    const int base = bid * 64;

    // hoisted edge metadata loads
    int s_e = 0, t_e = 0;
    if (MODE == 1) { s_e = src[base + l]; t_e = dst[base + l]; }

    const int srow = tid >> 2;                 // 0..63
    const int scg  = tid & 3;                  // 0..3
    int gr = base + srow; if (gr > M - 1) gr = M - 1;
    const float* xp = X + (size_t)gr * IN_F + scg * 16;

    float4 xs[4];
    #pragma unroll
    for (int q = 0; q < 4; ++q) xs[q] = *(const float4*)(xp + q * 4);

    auto cvtwrite = [&](int buf) {
        unsigned short h[16], lo[16];
        const float* xf = (const float*)xs;
        #pragma unroll
        for (int k = 0; k < 16; ++k) {
            h[k]  = f2bf(xf[k]);
            lo[k] = f2bf(xf[k] - bf2f(h[k]));
        }
        const unsigned sw = (unsigned)((srow & 7) << 4);
        const unsigned b0 = (unsigned)(srow * 128 + scg * 32) ^ sw;
        const unsigned b1 = (unsigned)(srow * 128 + scg * 32 + 16) ^ sw;
        char* ph = smem + (buf * 2 + 0) * 8192;
        char* pl = smem + (buf * 2 + 1) * 8192;
        *(bf16x8*)(ph + b0) = *(const bf16x8*)(h);
        *(bf16x8*)(ph + b1) = *(const bf16x8*)(h + 8);
        *(bf16x8*)(pl + b0) = *(const bf16x8*)(lo);
        *(bf16x8*)(pl + b1) = *(const bf16x8*)(lo + 8);
    };
    cvtwrite(0);

    // dependent gathers fly under chunk 0's MFMAs
    float a1v = 0.f, a2v = 0.f;
    if (MODE == 1) {
        a1v = a1[(size_t)s_e * HH + w];
        a2v = a2[(size_t)t_e * HH + w];
    }

    f32x4 acc[4][2];
    #pragma unroll
    for (int rf = 0; rf < 4; ++rf)
        #pragma unroll
        for (int cf = 0; cf < 2; ++cf)
            acc[rf][cf] = (f32x4){0.f, 0.f, 0.f, 0.f};

    #pragma unroll
    for (int c = 0; c < 4; ++c) {
        // B-frag loads for this chunk issued BEFORE the barrier: global-only,
        // no LDS dependence — latency overlaps the barrier drain.
        bf16x8 Bh[2][2], Bl[2][2];
        #pragma unroll
        for (int ks = 0; ks < 2; ++ks)
            #pragma unroll
            for (int cf = 0; cf < 2; ++cf) {
                size_t off = ((size_t)((c * 2 + ks) * 8 + (w * 2 + cf)) * 64 + l) * 8;
                Bh[ks][cf] = *(const bf16x8*)(Whp + off);
                Bl[ks][cf] = *(const bf16x8*)(Wlp + off);
            }
        __syncthreads();
        if (c < 3) {
            #pragma unroll
            for (int q = 0; q < 4; ++q)
                xs[q] = *(const float4*)(xp + (c + 1) * 64 + q * 4);
        }
        const char* ph = smem + ((c & 1) * 2 + 0) * 8192;
        const char* pl = smem + ((c & 1) * 2 + 1) * 8192;
        #pragma unroll
        for (int rf = 0; rf < 4; ++rf) {
            const int row = rf * 16 + (l & 15);
            const unsigned sw = (unsigned)((row & 7) << 4);
            #pragma unroll
            for (int ks = 0; ks < 2; ++ks) {
                const unsigned ba = (unsigned)(row * 128 + ks * 64 + (l >> 4) * 16) ^ sw;
                bf16x8 ah = *(const bf16x8*)(ph + ba);
                bf16x8 al = *(const bf16x8*)(pl + ba);
                #pragma unroll
                for (int cf = 0; cf < 2; ++cf) {
                    acc[rf][cf] = __builtin_amdgcn_mfma_f32_16x16x32_bf16(ah, Bh[ks][cf], acc[rf][cf], 0, 0, 0);
                    acc[rf][cf] = __builtin_amdgcn_mfma_f32_16x16x32_bf16(al, Bh[ks][cf], acc[rf][cf], 0, 0, 0);
                    acc[rf][cf] = __builtin_amdgcn_mfma_f32_16x16x32_bf16(ah, Bl[ks][cf], acc[rf][cf], 0, 0, 0);
                }
            }
        }
        if (c < 3) cvtwrite((c + 1) & 1);
    }

    // ---- MODE1: issue ft[src] gathers (hide under dot-reduce below) ----
    unsigned short ftv[4][2][4];
    if (MODE == 1) {
        int srow16[16];
        #pragma unroll
        for (int rf = 0; rf < 4; ++rf)
            #pragma unroll
            for (int r = 0; r < 4; ++r)
                srow16[rf * 4 + r] = src[base + rf * 16 + (l >> 4) * 4 + r];
        #pragma unroll
        for (int rf = 0; rf < 4; ++rf)
            #pragma unroll
            for (int cf = 0; cf < 2; ++cf)
                #pragma unroll
                for (int r = 0; r < 4; ++r)
                    ftv[rf][cf][r] = ftin[(size_t)srow16[rf * 4 + r] * OUT_F
                                          + w * 32 + cf * 16 + (l & 15)];
    }

    // ---- attention dots: register-only reduce (hides gather latency) ----
    const float b0 = av0[w * DD + (l & 15)];
    const float b1 = av0[w * DD + 16 + (l & 15)];
    float c0v = 0.f, c1v = 0.f;
    if (MODE == 0) { c0v = av1[w * DD + (l & 15)]; c1v = av1[w * DD + 16 + (l & 15)]; }

    float pv[4][4], qv[4][4];
    #pragma unroll
    for (int rf = 0; rf < 4; ++rf)
        #pragma unroll
        for (int r = 0; r < 4; ++r) {
            pv[rf][r] = acc[rf][0][r] * b0 + acc[rf][1][r] * b1;
            if (MODE == 0) qv[rf][r] = acc[rf][0][r] * c0v + acc[rf][1][r] * c1v;
        }
    #pragma unroll
    for (int o = 1; o <= 8; o <<= 1)
        #pragma unroll
        for (int rf = 0; rf < 4; ++rf)
            #pragma unroll
            for (int r = 0; r < 4; ++r) {
                pv[rf][r] += __shfl_xor(pv[rf][r], o);
                if (MODE == 0) qv[rf][r] += __shfl_xor(qv[rf][r], o);
            }

    // ---- store ft (MODE0) / sumb = e_ft + ft[src] (MODE1) as bf16 ----
    #pragma unroll
    for (int rf = 0; rf < 4; ++rf)
        #pragma unroll
        for (int cf = 0; cf < 2; ++cf)
            #pragma unroll
            for (int r = 0; r < 4; ++r) {
                int grow = base + rf * 16 + (l >> 4) * 4 + r;
                float v = acc[rf][cf][r];
                if (MODE == 1) v += bf2f(ftv[rf][cf][r]);
                if (MODE == 1 || grow < M)
                    Yh[(size_t)grow * OUT_F + w * 32 + cf * 16 + (l & 15)] = f2bf(v);
            }

    float* p_lds = (float*)smem;           // 1 KB overlay (A-tile dead)
    float* q_lds = (float*)(smem + 1024);
    __syncthreads();
    if ((l & 15) == 0) {
        const int hi = l >> 4;
        #pragma unroll
        for (int rf = 0; rf < 4; ++rf)
            #pragma unroll
            for (int r = 0; r < 4; ++r) {
                p_lds[w * 64 + rf * 16 + hi * 4 + r] = pv[rf][r];
                if (MODE == 0) q_lds[w * 64 + rf * 16 + hi * 4 + r] = qv[rf][r];
            }
    }
    __syncthreads();

    const int grow = base + l;
    if (MODE == 0) {
        if (grow < M) {
            o1[(size_t)grow * HH + w] = p_lds[w * 64 + l];
            o2[(size_t)grow * HH + w] = q_lds[w * 64 + l];
        }
    } else {
        float lg = p_lds[w * 64 + l] + a1v + a2v;
        lg = fmaxf(lg, ALPHA * lg);          // leaky_relu
        float exv = expf(lg);                // no max-shift (|lg|max ~70 << 88)
        o1[(size_t)grow * HH + w] = exv;     // [E][H]
        atomicAdd(&ssum[t_e * HH + w], exv);
    }
}

// 256-thread exclusive scan of hist[NN] -> cursor (single block).
__device__ __forceinline__ void scan_body(const int* __restrict__ hist,
        int* __restrict__ cursor) {
    __shared__ int part[256];
    const int t = threadIdx.x;
    const int CH = (NN + 255) / 256;          // 196
    const int b = t * CH;
    int s = 0;
    #pragma unroll 4
    for (int i = 0; i < CH; ++i) {
        int idx = b + i;
        if (idx < NN) s += hist[idx];
    }
    part[t] = s;
    __syncthreads();
    int total = s;
    for (int o = 1; o < 256; o <<= 1) {
        int u = (t >= o) ? part[t - o] : 0;
        __syncthreads();
        part[t] += u;
        __syncthreads();
    }
    int run = part[t] - total;                // exclusive base
    for (int i = 0; i < CH; ++i) {
        int idx = b + i;
        if (idx < NN) {
            cursor[idx] = run;
            run += hist[idx];
        }
    }
}

// node GEMM blocks ∥ scan block (cursor consumed only by NEXT kernel).
__global__ __launch_bounds__(256, 4) void k_ng(const float* __restrict__ nf,
        const unsigned short* __restrict__ Whp, const unsigned short* __restrict__ Wlp,
        const float* __restrict__ attn_l, const float* __restrict__ attn_r,
        unsigned short* __restrict__ ftb,
        float* __restrict__ a1buf, float* __restrict__ a2buf,
        const int* __restrict__ hist, int* __restrict__ cursor) {
    if (blockIdx.x < NODE_GB) {
        gemm_body<0>(blockIdx.x, nf, NN, Whp, Wlp, attn_l, attn_r,
                     nullptr, nullptr, nullptr, nullptr, nullptr,
                     ftb, a1buf, a2buf, nullptr);
    } else {
        scan_body(hist, cursor);
    }
}

// edge GEMM blocks ∥ scatter blocks
__global__ __launch_bounds__(256, 4) void k_eg(const float* __restrict__ ef,
        const unsigned short* __restrict__ Whp, const unsigned short* __restrict__ Wlp,
        const float* __restrict__ attn_e,
        const int* __restrict__ src, const int* __restrict__ dst,
        const float* __restrict__ a1buf, const float* __restrict__ a2buf,
        const unsigned short* __restrict__ ftb,
        unsigned short* __restrict__ sumb, float* __restrict__ exq,
        float* __restrict__ ssum,
        int* __restrict__ cursor, int* __restrict__ order) {
    if (blockIdx.x < EDGE_GB) {
        gemm_body<1>(blockIdx.x, ef, EE, Whp, Wlp, attn_e, nullptr,
                     src, dst, a1buf, a2buf, ftb, sumb, exq, nullptr, ssum);
    } else {
        int i = (blockIdx.x - EDGE_GB) * 256 + threadIdx.x;   // exactly EE
        int pos = atomicAdd(&cursor[dst[i]], 1);
        order[pos] = i;
    }
}

// Edge-centric aggregation over dst-sorted order[]. Block = 128 sorted edges,
// wave w owns rows [32w,32w+32). sumb holds e_ft+ft[src] (bf16). ret2 (never
// re-read) written with non-temporal stores so sumb/exq stay L3-resident.
__global__ __launch_bounds__(256, 8) void k_agg2(const int* __restrict__ order,
        const int* __restrict__ dst,
        const float* __restrict__ exq, const float* __restrict__ ssum,
        const unsigned short* __restrict__ sumb,
        float* __restrict__ ret2, float* __restrict__ node_out) {
    __shared__ int eL[AGG_BLK], dL[AGG_BLK];
    __shared__ int sent[2];
    const int tid = threadIdx.x;
    const int base = blockIdx.x * AGG_BLK;
    if (tid < AGG_BLK) {
        int e = order[base + tid];
        eL[tid] = e;
        dL[tid] = dst[e];
    } else if (tid == AGG_BLK) {
        sent[0] = (blockIdx.x > 0) ? dst[order[base - 1]] : -1;
    } else if (tid == AGG_BLK + 1) {
        sent[1] = (base + AGG_BLK < EE) ? dst[order[base + AGG_BLK]] : -1;
    }
    __syncthreads();

    const int w = tid >> 6, l = tid & 63;
    const int W0 = w * 32, W1 = W0 + 31;
    const int c0 = l * 2, h = l >> 4;

    const int dprev  = (W0 == 0)           ? sent[0] : dL[W0 - 1];
    const int dafter = (W1 == AGG_BLK - 1) ? sent[1] : dL[W1 + 1];

    float acc0 = 0.f, acc1 = 0.f;
    int dcur = dL[W0];
    bool touch_start = true;

    #pragma unroll 4
    for (int r = W0; r <= W1; ++r) {
        const int e = eL[r], d = dL[r];
        if (d != dcur) {       // wave-uniform: flush completed run
            const size_t o = (size_t)dcur * OUT_F + c0;
            if (touch_start && dcur == dprev) {
                atomicAdd(&node_out[o], acc0);
                atomicAdd(&node_out[o + 1], acc1);
            } else {
                *(float2*)(node_out + o) = make_float2(acc0, acc1);
            }
            acc0 = acc1 = 0.f; dcur = d; touch_start = false;
        }
        const float a = exq[(size_t)e * HH + h] * __frcp_rn(ssum[d * HH + h]);
        ushort2 sv = *(const ushort2*)(sumb + (size_t)e * OUT_F + c0);
        float f0 = bf2f(sv.x) * a;
        float f1 = bf2f(sv.y) * a;
        acc0 += f0; acc1 += f1;
        f32x2 outv = {elu_f(f0), elu_f(f1)};
        __builtin_nontemporal_store(outv, (f32x2*)(ret2 + (size_t)e * OUT_F + c0));
    }
    {
        const size_t o = (size_t)dcur * OUT_F + c0;
        const bool at = (touch_start && dcur == dprev) || (dcur == dafter);
        if (at) {
            atomicAdd(&node_out[o], acc0);
            atomicAdd(&node_out[o + 1], acc1);
        } else {
            *(float2*)(node_out + o) = make_float2(acc0, acc1);
        }
    }
}

__global__ __launch_bounds__(256) void k_elu1(const float4* __restrict__ node_out,
        float* __restrict__ ret1) {
    const int i = blockIdx.x * blockDim.x + threadIdx.x;
    if (i < NN * OUT_F / 4) {
        float4 v = node_out[i];
        f32x4 outv = {elu_f(v.x), elu_f(v.y), elu_f(v.z), elu_f(v.w)};
        __builtin_nontemporal_store(outv, (f32x4*)(ret1 + (size_t)i * 4));
    }
}

extern "C" void kernel_launch(void* const* d_in, const int* in_sizes, int n_in,
                              void* d_out, int out_size, void* d_ws, size_t ws_size,
                              hipStream_t stream) {
    const float* nf     = (const float*)d_in[0];
    const float* ef     = (const float*)d_in[1];
    const int*   src    = (const int*)d_in[2];
    const int*   dst    = (const int*)d_in[3];
    const float* W      = (const float*)d_in[4];
    const float* attn_l = (const float*)d_in[5];
    const float* attn_r = (const float*)d_in[6];
    const float* attn_e = (const float*)d_in[7];

    float* ret1 = (float*)d_out;                     // N*128, node_out accum
    float* ret2 = ret1 + (size_t)NN * OUT_F;         // E*128 output

    char* wsp = (char*)d_ws;
    auto take = [&](size_t bytes) { char* p = wsp; wsp += (bytes + 511) & ~size_t(511); return p; };
    unsigned short* ftb = (unsigned short*)take((size_t)NN * OUT_F * 2);  // 12.8 MB
    float* a1buf  = (float*)take((size_t)NN * HH * 4);
    float* a2buf  = (float*)take((size_t)NN * HH * 4);
    float* exq    = (float*)take((size_t)EE * HH * 4);      // 12.8 MB, [E][H]
    float* ssum   = (float*)take((size_t)NN * HH * 4);
    unsigned short* Whp = (unsigned short*)take(32768 * 2);
    unsigned short* Wlp = (unsigned short*)take(32768 * 2);
    int* hist   = (int*)take((size_t)(NN + 16) * 4);
    int* cursor = (int*)take((size_t)NN * 4);
    int* order  = (int*)take((size_t)EE * 4);               // 3.2 MB
    unsigned short* sumb = (unsigned short*)take((size_t)EE * OUT_F * 2); // 204.8 MB

    hipMemsetAsync(hist, 0, (size_t)NN * 4, stream);
    k_setup0<<<PREP_B + ZS_B + ZR_B + HIST_GB, 256, 0, stream>>>(
            W, Whp, Wlp, (float4*)ssum, (float4*)ret1, dst, hist);
    k_ng<<<NODE_GB + 1, 256, 0, stream>>>(nf, Whp, Wlp, attn_l, attn_r,
            ftb, a1buf, a2buf, hist, cursor);
    k_eg<<<EDGE_GB + SCAT_GB, 256, 0, stream>>>(ef, Whp, Wlp, attn_e,
            src, dst, a1buf, a2buf, ftb, sumb, exq, ssum, cursor, order);
    k_agg2<<<AGG_GB, 256, 0, stream>>>(order, dst, exq, ssum, sumb,
                                       ret2, ret1);
    k_elu1<<<(NN * OUT_F / 4 + 255) / 256, 256, 0, stream>>>(
            (const float4*)ret1, ret1);
}